// Round 1
// baseline (828.677 us; speedup 1.0000x reference)
//
#include <hip/hip_runtime.h>
#include <math.h>

#define N_NODES 100000
#define N_EDGES 1600000
#define IN_DIM 500
#define HID 64
#define NCLS 16

// ---------------------------------------------------------------------------
// K1: C = x @ B for B in {w1[0], w1[1], root1}; blockIdx.y selects which.
// BM=64, BN=64, BK=32, 256 threads, 4x4 per-thread register tile.
// As stored [k][m] padded to 68 to avoid LDS bank conflicts + keep 16B align.
// ---------------------------------------------------------------------------
__global__ __launch_bounds__(256) void k1_gemm(
    const float* __restrict__ x, const float* __restrict__ w1,
    const float* __restrict__ root1,
    float* __restrict__ xw0, float* __restrict__ xw1, float* __restrict__ aggH)
{
    const int which = blockIdx.y;
    const float* __restrict__ B =
        (which == 0) ? w1 : (which == 1) ? (w1 + IN_DIM * HID) : root1;
    float* __restrict__ C = (which == 0) ? xw0 : (which == 1) ? xw1 : aggH;
    const int row0 = blockIdx.x * 64;

    __shared__ float As[32][68];  // [k][m], pad 64->68 (16B aligned rows)
    __shared__ float Bs[32][64];  // [k][n]

    const int tid = threadIdx.x;
    const int kcol = tid & 31;   // A-load k within tile
    const int rbase = tid >> 5;  // A-load row base (8 rows, stride 8)
    const int bn = tid & 63;     // B-load col
    const int bk = tid >> 6;     // B-load k base (8 ks, stride 4)

    const int ty = tid >> 4;     // 0..15 row group (4 rows each)
    const int tx = tid & 15;     // 0..15 col group (4 cols each)

    float acc[4][4];
#pragma unroll
    for (int i = 0; i < 4; ++i)
#pragma unroll
        for (int j = 0; j < 4; ++j) acc[i][j] = 0.f;

    for (int k0 = 0; k0 < IN_DIM; k0 += 32) {
        // A tile: x[row][k] -> As[k][m]
#pragma unroll
        for (int r = 0; r < 8; ++r) {
            int row = row0 + rbase + r * 8;
            int k = k0 + kcol;
            float v = 0.f;
            if (row < N_NODES && k < IN_DIM) v = x[(size_t)row * IN_DIM + k];
            As[kcol][rbase + r * 8] = v;
        }
        // B tile: B[k][n] -> Bs[k][n] (coalesced)
#pragma unroll
        for (int r = 0; r < 8; ++r) {
            int k = k0 + bk + r * 4;
            float v = 0.f;
            if (k < IN_DIM) v = B[k * HID + bn];
            Bs[bk + r * 4][bn] = v;
        }
        __syncthreads();
#pragma unroll
        for (int kk = 0; kk < 32; ++kk) {
            float a[4], b[4];
#pragma unroll
            for (int i = 0; i < 4; ++i) a[i] = As[kk][ty * 4 + i];
#pragma unroll
            for (int j = 0; j < 4; ++j) b[j] = Bs[kk][tx * 4 + j];
#pragma unroll
            for (int i = 0; i < 4; ++i)
#pragma unroll
                for (int j = 0; j < 4; ++j) acc[i][j] += a[i] * b[j];
        }
        __syncthreads();
    }
#pragma unroll
    for (int i = 0; i < 4; ++i) {
        int row = row0 + ty * 4 + i;
        if (row < N_NODES) {
            float4 val = make_float4(acc[i][0], acc[i][1], acc[i][2], acc[i][3]);
            *reinterpret_cast<float4*>(&C[(size_t)row * HID + tx * 4]) = val;
        }
    }
}

// ---------------------------------------------------------------------------
// K2: per-edge blend + scatter-add into aggH (already holds x@root1).
// 64 lanes per edge (lane = hidden dim), 4 edges per block, grid-stride.
// ---------------------------------------------------------------------------
__global__ __launch_bounds__(256) void k2_edge1(
    const int* __restrict__ ei, const float* __restrict__ ea,
    const float* __restrict__ xw0, const float* __restrict__ xw1,
    float* __restrict__ aggH)
{
    const int d = threadIdx.x & 63;
    const int esub = threadIdx.x >> 6;
    for (int e0 = blockIdx.x * 4; e0 < N_EDGES; e0 += gridDim.x * 4) {
        int e = e0 + esub;
        int src = ei[e];
        int dst = ei[N_EDGES + e];
        float v = fminf(fmaxf(ea[e], 0.f), 1.f - 1e-6f);
        float m = (1.f - v) * xw0[(size_t)src * HID + d] +
                  v * xw1[(size_t)src * HID + d];
        atomicAdd(&aggH[(size_t)dst * HID + d], m);
    }
}

// ---------------------------------------------------------------------------
// K3: h = relu(aggH + b1); then hw0 = h@w2[0], hw1 = h@w2[1], agg2 = h@root2.
// 16 nodes per block; thread = (node_local, class).
// ---------------------------------------------------------------------------
__global__ __launch_bounds__(256) void k3_relu_gemm(
    const float* __restrict__ aggH, const float* __restrict__ b1,
    const float* __restrict__ w2, const float* __restrict__ root2,
    float* __restrict__ hw0, float* __restrict__ hw1, float* __restrict__ agg2)
{
    __shared__ float Ws[3 * HID * NCLS];  // 12KB: w2[0], w2[1], root2
    __shared__ float Hs[16][HID];         // 4KB

    const int tid = threadIdx.x;
    for (int i = tid; i < 2 * HID * NCLS; i += 256) Ws[i] = w2[i];
    for (int i = tid; i < HID * NCLS; i += 256) Ws[2 * HID * NCLS + i] = root2[i];

    const int n0 = blockIdx.x * 16;
    for (int i = tid; i < 16 * HID; i += 256) {
        int nl = i >> 6, k = i & 63;
        float h = aggH[(size_t)(n0 + nl) * HID + k] + b1[k];
        Hs[nl][k] = fmaxf(h, 0.f);
    }
    __syncthreads();

    const int nl = tid >> 4;
    const int c = tid & 15;
    float a0 = 0.f, a1 = 0.f, a2 = 0.f;
#pragma unroll
    for (int k = 0; k < HID; ++k) {
        float h = Hs[nl][k];
        a0 += h * Ws[0 * HID * NCLS + k * NCLS + c];
        a1 += h * Ws[1 * HID * NCLS + k * NCLS + c];
        a2 += h * Ws[2 * HID * NCLS + k * NCLS + c];
    }
    size_t o = (size_t)(n0 + nl) * NCLS + c;
    hw0[o] = a0;
    hw1[o] = a1;
    agg2[o] = a2;
}

// ---------------------------------------------------------------------------
// K4: layer-2 edge blend + scatter-add into agg2 (already holds h@root2).
// 16 lanes per edge, 16 edges per block, grid-stride.
// ---------------------------------------------------------------------------
__global__ __launch_bounds__(256) void k4_edge2(
    const int* __restrict__ ei, const float* __restrict__ ea,
    const float* __restrict__ hw0, const float* __restrict__ hw1,
    float* __restrict__ agg2)
{
    const int c = threadIdx.x & 15;
    const int esub = threadIdx.x >> 4;
    for (int e0 = blockIdx.x * 16; e0 < N_EDGES; e0 += gridDim.x * 16) {
        int e = e0 + esub;
        int src = ei[e];
        int dst = ei[N_EDGES + e];
        float v = fminf(fmaxf(ea[e], 0.f), 1.f - 1e-6f);
        float m = (1.f - v) * hw0[src * NCLS + c] + v * hw1[src * NCLS + c];
        atomicAdd(&agg2[dst * NCLS + c], m);
    }
}

// ---------------------------------------------------------------------------
// K5: out = log_softmax(agg2 + b2) over 16 classes. 16 lanes per node.
// ---------------------------------------------------------------------------
__global__ __launch_bounds__(256) void k5_logsoftmax(
    const float* __restrict__ agg2, const float* __restrict__ b2,
    float* __restrict__ out)
{
    const int n = blockIdx.x * 16 + (threadIdx.x >> 4);
    const int c = threadIdx.x & 15;
    float z = agg2[n * NCLS + c] + b2[c];
    float m = z;
#pragma unroll
    for (int s = 1; s < 16; s <<= 1) m = fmaxf(m, __shfl_xor(m, s, 64));
    float e = expf(z - m);
    float ssum = e;
#pragma unroll
    for (int s = 1; s < 16; s <<= 1) ssum += __shfl_xor(ssum, s, 64);
    out[n * NCLS + c] = (z - m) - logf(ssum);
}

extern "C" void kernel_launch(void* const* d_in, const int* in_sizes, int n_in,
                              void* d_out, int out_size, void* d_ws, size_t ws_size,
                              hipStream_t stream) {
    const float* x = (const float*)d_in[0];
    const int* ei = (const int*)d_in[1];
    const float* ea = (const float*)d_in[2];
    const float* w1 = (const float*)d_in[3];
    const float* root1 = (const float*)d_in[4];
    const float* b1 = (const float*)d_in[5];
    const float* w2 = (const float*)d_in[6];
    const float* root2 = (const float*)d_in[7];
    const float* b2 = (const float*)d_in[8];
    float* out = (float*)d_out;

    float* ws = (float*)d_ws;
    float* xw0 = ws;                                   // N*64
    float* xw1 = xw0 + (size_t)N_NODES * HID;          // N*64
    float* aggH = xw1 + (size_t)N_NODES * HID;         // N*64
    float* hw0 = aggH + (size_t)N_NODES * HID;         // N*16
    float* hw1 = hw0 + (size_t)N_NODES * NCLS;         // N*16
    float* agg2 = hw1 + (size_t)N_NODES * NCLS;        // N*16

    dim3 g1((N_NODES + 63) / 64, 3);
    k1_gemm<<<g1, 256, 0, stream>>>(x, w1, root1, xw0, xw1, aggH);
    k2_edge1<<<4096, 256, 0, stream>>>(ei, ea, xw0, xw1, aggH);
    k3_relu_gemm<<<N_NODES / 16, 256, 0, stream>>>(aggH, b1, w2, root2, hw0, hw1, agg2);
    k4_edge2<<<4096, 256, 0, stream>>>(ei, ea, hw0, hw1, agg2);
    k5_logsoftmax<<<N_NODES / 16, 256, 0, stream>>>(agg2, b2, out);
}

// Round 2
// 578.370 us; speedup vs baseline: 1.4328x; 1.4328x over previous
//
#include <hip/hip_runtime.h>
#include <math.h>

#define N_NODES 100000
#define N_EDGES 1600000
#define IN_DIM 500
#define HID 64
#define NCLS 16
#define KP 512     // padded K for layer-1 GEMM
#define NSTEPS 16  // KP/32

typedef __attribute__((ext_vector_type(8))) short short8;
typedef __attribute__((ext_vector_type(4))) float f32x4;

__device__ __forceinline__ unsigned short f2bf(float f) {
    unsigned u = __builtin_bit_cast(unsigned, f);
    return (unsigned short)((u + 0x7FFFu + ((u >> 16) & 1u)) >> 16);
}
__device__ __forceinline__ float bf2f(unsigned short s) {
    unsigned u = ((unsigned)s) << 16;
    return __builtin_bit_cast(float, u);
}
__device__ __forceinline__ unsigned pack2(unsigned short a, unsigned short b) {
    return (unsigned)a | ((unsigned)b << 16);
}

// ---------------------------------------------------------------------------
// K0: build Bt[192][512] bf16 = transpose of {w1[0], w1[1], root1}, zero-pad K.
// One block per output column.
// ---------------------------------------------------------------------------
__global__ __launch_bounds__(256) void k0_bt(
    const float* __restrict__ w1, const float* __restrict__ root1,
    unsigned short* __restrict__ Bt)
{
    const int b = blockIdx.x;  // 0..191
    const float* src;
    int c;
    if (b < 64)        { src = w1;                c = b; }
    else if (b < 128)  { src = w1 + IN_DIM * HID; c = b - 64; }
    else               { src = root1;             c = b - 128; }
    for (int k = threadIdx.x; k < KP; k += 256) {
        float v = (k < IN_DIM) ? src[k * HID + c] : 0.f;
        Bt[b * KP + k] = f2bf(v);
    }
}

// ---------------------------------------------------------------------------
// K1: bf16 MFMA GEMM. C[128 x 192] per block = x_tile @ Bt^T.
// cols 0..127 -> interleaved bf16 xw01[node][d][{0,1}], cols 128..191 -> aggH f32.
// 256 threads = 4 waves; wave w owns rows w*32..w*32+32 (2 row-frags x 12 col-frags).
// ---------------------------------------------------------------------------
union K1Smem {
    struct { unsigned short A[128 * 40]; unsigned short B[192 * 40]; } ab;
    unsigned short O[64 * 264];  // 64-row bf16 out-staging (interleaved, padded)
};

__global__ __launch_bounds__(256) void k1_mfma(
    const float* __restrict__ x, const unsigned short* __restrict__ Bt,
    unsigned short* __restrict__ xw01, float* __restrict__ aggH)
{
    __shared__ K1Smem sm;

    const int tid = threadIdx.x;
    const int row0 = blockIdx.x * 128;
    const int w = tid >> 6;
    const int l = tid & 63;
    const int l16 = l & 15;
    const int koct = l >> 4;  // 0..3

    f32x4 acc[2][12];
#pragma unroll
    for (int i = 0; i < 2; ++i)
#pragma unroll
        for (int j = 0; j < 12; ++j) acc[i][j] = (f32x4){0.f, 0.f, 0.f, 0.f};

    const int arow = tid >> 1;   // 0..127
    const int ahalf = tid & 1;   // 0..1

    for (int s = 0; s < NSTEPS; ++s) {
        const int k0 = s * 32;
        // --- stage A tile: x[row0..row0+128) x [k0, k0+32) -> bf16 LDS ---
        {
            const bool rv = (row0 + arow) < N_NODES;
            const float* src = x + (size_t)(row0 + arow) * IN_DIM + k0 + ahalf * 16;
            unsigned short t16[16];
#pragma unroll
            for (int j = 0; j < 4; ++j) {
                const int k = k0 + ahalf * 16 + j * 4;
                float4 v = make_float4(0.f, 0.f, 0.f, 0.f);
                if (rv && k < IN_DIM) v = *(const float4*)(src + j * 4);
                t16[j * 4 + 0] = f2bf(v.x);
                t16[j * 4 + 1] = f2bf(v.y);
                t16[j * 4 + 2] = f2bf(v.z);
                t16[j * 4 + 3] = f2bf(v.w);
            }
            uint4 w0, w1v;
            w0.x = pack2(t16[0], t16[1]);  w0.y = pack2(t16[2], t16[3]);
            w0.z = pack2(t16[4], t16[5]);  w0.w = pack2(t16[6], t16[7]);
            w1v.x = pack2(t16[8], t16[9]); w1v.y = pack2(t16[10], t16[11]);
            w1v.z = pack2(t16[12], t16[13]); w1v.w = pack2(t16[14], t16[15]);
            *(uint4*)&sm.ab.A[arow * 40 + ahalf * 16] = w0;
            *(uint4*)&sm.ab.A[arow * 40 + ahalf * 16 + 8] = w1v;
        }
        // --- stage B tile: Bt[col][k0..k0+32) -> LDS ---
#pragma unroll
        for (int i = 0; i < 3; ++i) {
            const int id = tid + i * 256;  // 0..767
            const int col = id >> 2, c = id & 3;
            uint4 v = *(const uint4*)&Bt[col * KP + k0 + c * 8];
            *(uint4*)&sm.ab.B[col * 40 + c * 8] = v;
        }
        __syncthreads();

        short8 af[2];
#pragma unroll
        for (int rb = 0; rb < 2; ++rb)
            af[rb] = *(const short8*)&sm.ab.A[(w * 32 + rb * 16 + l16) * 40 + koct * 8];
#pragma unroll
        for (int cf = 0; cf < 12; ++cf) {
            short8 bfg = *(const short8*)&sm.ab.B[(cf * 16 + l16) * 40 + koct * 8];
            acc[0][cf] = __builtin_amdgcn_mfma_f32_16x16x32_bf16(af[0], bfg, acc[0][cf], 0, 0, 0);
            acc[1][cf] = __builtin_amdgcn_mfma_f32_16x16x32_bf16(af[1], bfg, acc[1][cf], 0, 0, 0);
        }
        __syncthreads();
    }

    // --- epilogue: aggH (cols 128..191) fp32 direct ---
#pragma unroll
    for (int rb = 0; rb < 2; ++rb)
#pragma unroll
        for (int cf = 8; cf < 12; ++cf)
#pragma unroll
            for (int reg = 0; reg < 4; ++reg) {
                const int r = row0 + w * 32 + rb * 16 + koct * 4 + reg;
                const int c = (cf - 8) * 16 + l16;
                if (r < N_NODES) aggH[(size_t)r * HID + c] = acc[rb][cf][reg];
            }

    // --- epilogue: xw01 (cols 0..127) -> bf16 interleaved via LDS, 2 passes ---
    for (int p = 0; p < 2; ++p) {
        __syncthreads();
        if ((w >> 1) == p) {
            const int wl = w & 1;
#pragma unroll
            for (int rb = 0; rb < 2; ++rb)
#pragma unroll
                for (int cf = 0; cf < 8; ++cf)
#pragma unroll
                    for (int reg = 0; reg < 4; ++reg) {
                        const int rloc = wl * 32 + rb * 16 + koct * 4 + reg;  // 0..63
                        const int cg = cf * 16 + l16;                          // 0..127
                        const int idx = (cg < 64) ? (2 * cg) : (2 * cg - 127);
                        sm.O[rloc * 264 + idx] = f2bf(acc[rb][cf][reg]);
                    }
        }
        __syncthreads();
        const int row = tid >> 2, q = tid & 3;
        const int rg = row0 + p * 64 + row;
        if (rg < N_NODES) {
#pragma unroll
            for (int j = 0; j < 4; ++j) {
                uint4 v = *(const uint4*)&sm.O[row * 264 + q * 32 + j * 8];
                *(uint4*)&xw01[(size_t)rg * 128 + q * 32 + j * 8] = v;
            }
        }
    }
}

// ---------------------------------------------------------------------------
// K2: per-edge blend + scatter-add into aggH. 64 lanes/edge, packed bf16 gather.
// ---------------------------------------------------------------------------
__global__ __launch_bounds__(256) void k2_edge1(
    const int* __restrict__ ei, const float* __restrict__ ea,
    const unsigned* __restrict__ xw01_u, float* __restrict__ aggH)
{
    const int d = threadIdx.x & 63;
    const int esub = threadIdx.x >> 6;
    for (int e0 = blockIdx.x * 4; e0 < N_EDGES; e0 += gridDim.x * 4) {
        const int e = e0 + esub;
        if (e >= N_EDGES) continue;
        const int src = ei[e];
        const int dst = ei[N_EDGES + e];
        const float v = fminf(fmaxf(ea[e], 0.f), 1.f - 1e-6f);
        const unsigned u = xw01_u[(size_t)src * 64 + d];
        const float a = bf2f((unsigned short)(u & 0xFFFF));
        const float b = bf2f((unsigned short)(u >> 16));
        const float m = (1.f - v) * a + v * b;
        atomicAdd(&aggH[(size_t)dst * HID + d], m);
    }
}

// ---------------------------------------------------------------------------
// K3: h = relu(aggH + b1); hw01 = packed bf16 {h@w2[0], h@w2[1]}; agg2 = h@root2.
// ---------------------------------------------------------------------------
__global__ __launch_bounds__(256) void k3_relu_gemm(
    const float* __restrict__ aggH, const float* __restrict__ b1,
    const float* __restrict__ w2, const float* __restrict__ root2,
    unsigned* __restrict__ hw01_u, float* __restrict__ agg2)
{
    __shared__ float Ws[3 * HID * NCLS];
    __shared__ float Hs[16][HID];

    const int tid = threadIdx.x;
    for (int i = tid; i < 2 * HID * NCLS; i += 256) Ws[i] = w2[i];
    for (int i = tid; i < HID * NCLS; i += 256) Ws[2 * HID * NCLS + i] = root2[i];

    const int n0 = blockIdx.x * 16;
    for (int i = tid; i < 16 * HID; i += 256) {
        const int nl = i >> 6, k = i & 63;
        const float h = aggH[(size_t)(n0 + nl) * HID + k] + b1[k];
        Hs[nl][k] = fmaxf(h, 0.f);
    }
    __syncthreads();

    const int nl = tid >> 4;
    const int c = tid & 15;
    float a0 = 0.f, a1 = 0.f, a2 = 0.f;
#pragma unroll
    for (int k = 0; k < HID; ++k) {
        const float h = Hs[nl][k];
        a0 += h * Ws[0 * HID * NCLS + k * NCLS + c];
        a1 += h * Ws[1 * HID * NCLS + k * NCLS + c];
        a2 += h * Ws[2 * HID * NCLS + k * NCLS + c];
    }
    const size_t o = (size_t)(n0 + nl) * NCLS + c;
    hw01_u[o] = pack2(f2bf(a0), f2bf(a1));
    agg2[o] = a2;
}

// ---------------------------------------------------------------------------
// K4: layer-2 edge blend + scatter-add. 16 lanes/edge, packed bf16 gather.
// ---------------------------------------------------------------------------
__global__ __launch_bounds__(256) void k4_edge2(
    const int* __restrict__ ei, const float* __restrict__ ea,
    const unsigned* __restrict__ hw01_u, float* __restrict__ agg2)
{
    const int c = threadIdx.x & 15;
    const int esub = threadIdx.x >> 4;
    for (int e0 = blockIdx.x * 16; e0 < N_EDGES; e0 += gridDim.x * 16) {
        const int e = e0 + esub;
        if (e >= N_EDGES) continue;
        const int src = ei[e];
        const int dst = ei[N_EDGES + e];
        const float v = fminf(fmaxf(ea[e], 0.f), 1.f - 1e-6f);
        const unsigned u = hw01_u[(size_t)src * NCLS + c];
        const float a = bf2f((unsigned short)(u & 0xFFFF));
        const float b = bf2f((unsigned short)(u >> 16));
        const float m = (1.f - v) * a + v * b;
        atomicAdd(&agg2[(size_t)dst * NCLS + c], m);
    }
}

// ---------------------------------------------------------------------------
// K5: out = log_softmax(agg2 + b2). 16 lanes per node.
// ---------------------------------------------------------------------------
__global__ __launch_bounds__(256) void k5_logsoftmax(
    const float* __restrict__ agg2, const float* __restrict__ b2,
    float* __restrict__ out)
{
    const int n = blockIdx.x * 16 + (threadIdx.x >> 4);
    const int c = threadIdx.x & 15;
    const float z = agg2[(size_t)n * NCLS + c] + b2[c];
    float m = z;
#pragma unroll
    for (int s = 1; s < 16; s <<= 1) m = fmaxf(m, __shfl_xor(m, s, 64));
    const float e = expf(z - m);
    float ssum = e;
#pragma unroll
    for (int s = 1; s < 16; s <<= 1) ssum += __shfl_xor(ssum, s, 64);
    out[(size_t)n * NCLS + c] = (z - m) - logf(ssum);
}

extern "C" void kernel_launch(void* const* d_in, const int* in_sizes, int n_in,
                              void* d_out, int out_size, void* d_ws, size_t ws_size,
                              hipStream_t stream) {
    const float* x = (const float*)d_in[0];
    const int* ei = (const int*)d_in[1];
    const float* ea = (const float*)d_in[2];
    const float* w1 = (const float*)d_in[3];
    const float* root1 = (const float*)d_in[4];
    const float* b1 = (const float*)d_in[5];
    const float* w2 = (const float*)d_in[6];
    const float* root2 = (const float*)d_in[7];
    const float* b2 = (const float*)d_in[8];
    float* out = (float*)d_out;

    char* ws = (char*)d_ws;
    unsigned short* xw01 = (unsigned short*)ws;                       // N*128 bf16 = 25.6 MB
    float* aggH = (float*)(ws + 25600000);                            // N*64 f32  = 25.6 MB
    unsigned* hw01_u = (unsigned*)(ws + 51200000);                    // N*16 u32  = 6.4 MB
    float* agg2 = (float*)(ws + 57600000);                            // N*16 f32  = 6.4 MB
    unsigned short* Bt = (unsigned short*)(ws + 64000000);            // 192*512 bf16

    k0_bt<<<192, 256, 0, stream>>>(w1, root1, Bt);
    k1_mfma<<<(N_NODES + 127) / 128, 256, 0, stream>>>(x, Bt, xw01, aggH);
    k2_edge1<<<8192, 256, 0, stream>>>(ei, ea, (const unsigned*)xw01, aggH);
    k3_relu_gemm<<<N_NODES / 16, 256, 0, stream>>>(aggH, b1, w2, root2, hw01_u, agg2);
    k4_edge2<<<8192, 256, 0, stream>>>(ei, ea, hw01_u, agg2);
    k5_logsoftmax<<<N_NODES / 16, 256, 0, stream>>>(agg2, b2, out);
}

// Round 3
// 415.471 us; speedup vs baseline: 1.9946x; 1.3921x over previous
//
#include <hip/hip_runtime.h>
#include <math.h>

#define N_NODES 100000
#define N_EDGES 1600000
#define IN_DIM 500
#define HID 64
#define NCLS 16
#define KP 512     // padded K for layer-1 GEMM
#define NSTEPS 16  // KP/32
#define NB_SCAN 391  // ceil(100000/256)
#define NPAD (NB_SCAN * 256)

typedef __attribute__((ext_vector_type(8))) short short8;
typedef __attribute__((ext_vector_type(4))) float f32x4;

__device__ __forceinline__ unsigned short f2bf(float f) {
    unsigned u = __builtin_bit_cast(unsigned, f);
    return (unsigned short)((u + 0x7FFFu + ((u >> 16) & 1u)) >> 16);
}
__device__ __forceinline__ float bf2f(unsigned short s) {
    unsigned u = ((unsigned)s) << 16;
    return __builtin_bit_cast(float, u);
}
__device__ __forceinline__ unsigned pack2(unsigned short a, unsigned short b) {
    return (unsigned)a | ((unsigned)b << 16);
}

// ---------------------------------------------------------------------------
// K0: build Bt[192][512] bf16 = transpose of {w1[0], w1[1], root1}, zero-pad K.
// ---------------------------------------------------------------------------
__global__ __launch_bounds__(256) void k0_bt(
    const float* __restrict__ w1, const float* __restrict__ root1,
    unsigned short* __restrict__ Bt)
{
    const int b = blockIdx.x;  // 0..191
    const float* src;
    int c;
    if (b < 64)        { src = w1;                c = b; }
    else if (b < 128)  { src = w1 + IN_DIM * HID; c = b - 64; }
    else               { src = root1;             c = b - 128; }
    for (int k = threadIdx.x; k < KP; k += 256) {
        float v = (k < IN_DIM) ? src[k * HID + c] : 0.f;
        Bt[b * KP + k] = f2bf(v);
    }
}

// ---------------------------------------------------------------------------
// CSR build: zero, histogram, scan x3, scatter
// ---------------------------------------------------------------------------
__global__ __launch_bounds__(256) void csr_zero(int* __restrict__ cnt)
{
    const int i = blockIdx.x * 256 + threadIdx.x;
    if (i < NPAD) cnt[i] = 0;
}

__global__ __launch_bounds__(256) void csr_hist(
    const int* __restrict__ ei, int* __restrict__ cnt)
{
    for (int e = blockIdx.x * 256 + threadIdx.x; e < N_EDGES; e += gridDim.x * 256)
        atomicAdd(&cnt[ei[N_EDGES + e]], 1);
}

// block-local exclusive scan; off[i] = exclusive within block; bsum[blk] = block total
__global__ __launch_bounds__(256) void csr_scan1(
    const int* __restrict__ cnt, int* __restrict__ off, int* __restrict__ bsum)
{
    __shared__ int s[256];
    const int t = threadIdx.x;
    const int i = blockIdx.x * 256 + t;
    const int val = cnt[i];
    s[t] = val;
    for (int d = 1; d < 256; d <<= 1) {
        __syncthreads();
        int add = (t >= d) ? s[t - d] : 0;
        __syncthreads();
        s[t] += add;
    }
    __syncthreads();
    off[i] = s[t] - val;
    if (t == 255) bsum[blockIdx.x] = s[255];
}

// single-block scan of block sums -> exclusive offsets
__global__ __launch_bounds__(512) void csr_scan2(
    const int* __restrict__ bsum, int* __restrict__ bsumoff)
{
    __shared__ int s[512];
    const int t = threadIdx.x;
    const int val = (t < NB_SCAN) ? bsum[t] : 0;
    s[t] = val;
    for (int d = 1; d < 512; d <<= 1) {
        __syncthreads();
        int add = (t >= d) ? s[t - d] : 0;
        __syncthreads();
        s[t] += add;
    }
    __syncthreads();
    if (t < NB_SCAN) bsumoff[t] = s[t] - val;
}

__global__ __launch_bounds__(256) void csr_scan3(
    int* __restrict__ off, const int* __restrict__ bsumoff, int* __restrict__ cursor)
{
    const int i = blockIdx.x * 256 + threadIdx.x;
    const int o = off[i] + bsumoff[blockIdx.x];
    off[i] = o;
    cursor[i] = o;
}

// scatter edge payload (src, clipped v) into dst-sorted order
__global__ __launch_bounds__(256) void csr_scatter(
    const int* __restrict__ ei, const float* __restrict__ ea,
    int* __restrict__ cursor, uint2* __restrict__ epk)
{
    for (int e = blockIdx.x * 256 + threadIdx.x; e < N_EDGES; e += gridDim.x * 256) {
        const int src = ei[e];
        const int dst = ei[N_EDGES + e];
        const float v = fminf(fmaxf(ea[e], 0.f), 1.f - 1e-6f);
        const int pos = atomicAdd(&cursor[dst], 1);
        epk[pos] = make_uint2((unsigned)src, __builtin_bit_cast(unsigned, v));
    }
}

// ---------------------------------------------------------------------------
// K1: bf16 MFMA GEMM. C[128 x 192] per block = x_tile @ Bt^T.
// ---------------------------------------------------------------------------
union K1Smem {
    struct { unsigned short A[128 * 40]; unsigned short B[192 * 40]; } ab;
    unsigned short O[64 * 264];
};

__global__ __launch_bounds__(256) void k1_mfma(
    const float* __restrict__ x, const unsigned short* __restrict__ Bt,
    unsigned short* __restrict__ xw01, float* __restrict__ aggH)
{
    __shared__ K1Smem sm;

    const int tid = threadIdx.x;
    const int row0 = blockIdx.x * 128;
    const int w = tid >> 6;
    const int l = tid & 63;
    const int l16 = l & 15;
    const int koct = l >> 4;

    f32x4 acc[2][12];
#pragma unroll
    for (int i = 0; i < 2; ++i)
#pragma unroll
        for (int j = 0; j < 12; ++j) acc[i][j] = (f32x4){0.f, 0.f, 0.f, 0.f};

    const int arow = tid >> 1;
    const int ahalf = tid & 1;

    for (int s = 0; s < NSTEPS; ++s) {
        const int k0 = s * 32;
        {
            const bool rv = (row0 + arow) < N_NODES;
            const float* src = x + (size_t)(row0 + arow) * IN_DIM + k0 + ahalf * 16;
            unsigned short t16[16];
#pragma unroll
            for (int j = 0; j < 4; ++j) {
                const int k = k0 + ahalf * 16 + j * 4;
                float4 v = make_float4(0.f, 0.f, 0.f, 0.f);
                if (rv && k < IN_DIM) v = *(const float4*)(src + j * 4);
                t16[j * 4 + 0] = f2bf(v.x);
                t16[j * 4 + 1] = f2bf(v.y);
                t16[j * 4 + 2] = f2bf(v.z);
                t16[j * 4 + 3] = f2bf(v.w);
            }
            uint4 w0, w1v;
            w0.x = pack2(t16[0], t16[1]);  w0.y = pack2(t16[2], t16[3]);
            w0.z = pack2(t16[4], t16[5]);  w0.w = pack2(t16[6], t16[7]);
            w1v.x = pack2(t16[8], t16[9]); w1v.y = pack2(t16[10], t16[11]);
            w1v.z = pack2(t16[12], t16[13]); w1v.w = pack2(t16[14], t16[15]);
            *(uint4*)&sm.ab.A[arow * 40 + ahalf * 16] = w0;
            *(uint4*)&sm.ab.A[arow * 40 + ahalf * 16 + 8] = w1v;
        }
#pragma unroll
        for (int i = 0; i < 3; ++i) {
            const int id = tid + i * 256;
            const int col = id >> 2, c = id & 3;
            uint4 v = *(const uint4*)&Bt[col * KP + k0 + c * 8];
            *(uint4*)&sm.ab.B[col * 40 + c * 8] = v;
        }
        __syncthreads();

        short8 af[2];
#pragma unroll
        for (int rb = 0; rb < 2; ++rb)
            af[rb] = *(const short8*)&sm.ab.A[(w * 32 + rb * 16 + l16) * 40 + koct * 8];
#pragma unroll
        for (int cf = 0; cf < 12; ++cf) {
            short8 bfg = *(const short8*)&sm.ab.B[(cf * 16 + l16) * 40 + koct * 8];
            acc[0][cf] = __builtin_amdgcn_mfma_f32_16x16x32_bf16(af[0], bfg, acc[0][cf], 0, 0, 0);
            acc[1][cf] = __builtin_amdgcn_mfma_f32_16x16x32_bf16(af[1], bfg, acc[1][cf], 0, 0, 0);
        }
        __syncthreads();
    }

#pragma unroll
    for (int rb = 0; rb < 2; ++rb)
#pragma unroll
        for (int cf = 8; cf < 12; ++cf)
#pragma unroll
            for (int reg = 0; reg < 4; ++reg) {
                const int r = row0 + w * 32 + rb * 16 + koct * 4 + reg;
                const int c = (cf - 8) * 16 + l16;
                if (r < N_NODES) aggH[(size_t)r * HID + c] = acc[rb][cf][reg];
            }

    for (int p = 0; p < 2; ++p) {
        __syncthreads();
        if ((w >> 1) == p) {
            const int wl = w & 1;
#pragma unroll
            for (int rb = 0; rb < 2; ++rb)
#pragma unroll
                for (int cf = 0; cf < 8; ++cf)
#pragma unroll
                    for (int reg = 0; reg < 4; ++reg) {
                        const int rloc = wl * 32 + rb * 16 + koct * 4 + reg;
                        const int cg = cf * 16 + l16;
                        const int idx = (cg < 64) ? (2 * cg) : (2 * cg - 127);
                        sm.O[rloc * 264 + idx] = f2bf(acc[rb][cf][reg]);
                    }
        }
        __syncthreads();
        const int row = tid >> 2, q = tid & 3;
        const int rg = row0 + p * 64 + row;
        if (rg < N_NODES) {
#pragma unroll
            for (int j = 0; j < 4; ++j) {
                uint4 v = *(const uint4*)&sm.O[row * 264 + q * 32 + j * 8];
                *(uint4*)&xw01[(size_t)rg * 128 + q * 32 + j * 8] = v;
            }
        }
    }
}

// ---------------------------------------------------------------------------
// AGG1: wave per node; lane = hidden dim. acc = aggH(root) + sum over edges.
// 4 edges in flight. No atomics.
// ---------------------------------------------------------------------------
__global__ __launch_bounds__(256) void agg1(
    const int* __restrict__ off, const int* __restrict__ cnt,
    const uint2* __restrict__ epk, const unsigned* __restrict__ xw01_u,
    float* __restrict__ aggH)
{
    const int n = blockIdx.x * 4 + (threadIdx.x >> 6);
    if (n >= N_NODES) return;
    const int d = threadIdx.x & 63;
    const int start = off[n];
    const int deg = cnt[n];

    float acc = aggH[(size_t)n * HID + d];
    for (int i = 0; i < deg; i += 4) {
        unsigned srcs[4];
        float w0[4], w1[4];
#pragma unroll
        for (int j = 0; j < 4; ++j) {
            const bool ok = (i + j) < deg;
            const int idx = ok ? (start + i + j) : start;
            const uint2 t = epk[idx];
            const float v = __builtin_bit_cast(float, t.y);
            srcs[j] = t.x;
            w0[j] = ok ? (1.f - v) : 0.f;
            w1[j] = ok ? v : 0.f;
        }
        unsigned g[4];
#pragma unroll
        for (int j = 0; j < 4; ++j) g[j] = xw01_u[(size_t)srcs[j] * 64 + d];
#pragma unroll
        for (int j = 0; j < 4; ++j) {
            acc += w0[j] * bf2f((unsigned short)(g[j] & 0xFFFF));
            acc += w1[j] * bf2f((unsigned short)(g[j] >> 16));
        }
    }
    aggH[(size_t)n * HID + d] = acc;
}

// ---------------------------------------------------------------------------
// K3: h = relu(aggH + b1); hw01 = packed bf16 {h@w2[0], h@w2[1]}; agg2 = h@root2.
// ---------------------------------------------------------------------------
__global__ __launch_bounds__(256) void k3_relu_gemm(
    const float* __restrict__ aggH, const float* __restrict__ b1,
    const float* __restrict__ w2, const float* __restrict__ root2,
    unsigned* __restrict__ hw01_u, float* __restrict__ agg2)
{
    __shared__ float Ws[3 * HID * NCLS];
    __shared__ float Hs[16][HID];

    const int tid = threadIdx.x;
    for (int i = tid; i < 2 * HID * NCLS; i += 256) Ws[i] = w2[i];
    for (int i = tid; i < HID * NCLS; i += 256) Ws[2 * HID * NCLS + i] = root2[i];

    const int n0 = blockIdx.x * 16;
    for (int i = tid; i < 16 * HID; i += 256) {
        const int nl = i >> 6, k = i & 63;
        const float h = aggH[(size_t)(n0 + nl) * HID + k] + b1[k];
        Hs[nl][k] = fmaxf(h, 0.f);
    }
    __syncthreads();

    const int nl = tid >> 4;
    const int c = tid & 15;
    float a0 = 0.f, a1 = 0.f, a2 = 0.f;
#pragma unroll
    for (int k = 0; k < HID; ++k) {
        const float h = Hs[nl][k];
        a0 += h * Ws[0 * HID * NCLS + k * NCLS + c];
        a1 += h * Ws[1 * HID * NCLS + k * NCLS + c];
        a2 += h * Ws[2 * HID * NCLS + k * NCLS + c];
    }
    const size_t o = (size_t)(n0 + nl) * NCLS + c;
    hw01_u[o] = pack2(f2bf(a0), f2bf(a1));
    agg2[o] = a2;
}

// ---------------------------------------------------------------------------
// AGG2 + log_softmax fused: 16 lanes per node, 16 nodes per block.
// ---------------------------------------------------------------------------
__global__ __launch_bounds__(256) void agg2_sm(
    const int* __restrict__ off, const int* __restrict__ cnt,
    const uint2* __restrict__ epk, const unsigned* __restrict__ hw01_u,
    const float* __restrict__ agg2, const float* __restrict__ b2,
    float* __restrict__ out)
{
    const int n = blockIdx.x * 16 + (threadIdx.x >> 4);
    const int c = threadIdx.x & 15;
    const int start = off[n];
    const int deg = cnt[n];

    float acc = agg2[(size_t)n * NCLS + c];
    for (int i = 0; i < deg; i += 4) {
        unsigned srcs[4];
        float w0[4], w1[4];
#pragma unroll
        for (int j = 0; j < 4; ++j) {
            const bool ok = (i + j) < deg;
            const int idx = ok ? (start + i + j) : start;
            const uint2 t = epk[idx];
            const float v = __builtin_bit_cast(float, t.y);
            srcs[j] = t.x;
            w0[j] = ok ? (1.f - v) : 0.f;
            w1[j] = ok ? v : 0.f;
        }
        unsigned g[4];
#pragma unroll
        for (int j = 0; j < 4; ++j) g[j] = hw01_u[(size_t)srcs[j] * NCLS + c];
#pragma unroll
        for (int j = 0; j < 4; ++j) {
            acc += w0[j] * bf2f((unsigned short)(g[j] & 0xFFFF));
            acc += w1[j] * bf2f((unsigned short)(g[j] >> 16));
        }
    }

    const float z = acc + b2[c];
    float m = z;
#pragma unroll
    for (int s = 1; s < 16; s <<= 1) m = fmaxf(m, __shfl_xor(m, s, 64));
    const float e = expf(z - m);
    float ssum = e;
#pragma unroll
    for (int s = 1; s < 16; s <<= 1) ssum += __shfl_xor(ssum, s, 64);
    out[(size_t)n * NCLS + c] = (z - m) - logf(ssum);
}

extern "C" void kernel_launch(void* const* d_in, const int* in_sizes, int n_in,
                              void* d_out, int out_size, void* d_ws, size_t ws_size,
                              hipStream_t stream) {
    const float* x = (const float*)d_in[0];
    const int* ei = (const int*)d_in[1];
    const float* ea = (const float*)d_in[2];
    const float* w1 = (const float*)d_in[3];
    const float* root1 = (const float*)d_in[4];
    const float* b1 = (const float*)d_in[5];
    const float* w2 = (const float*)d_in[6];
    const float* root2 = (const float*)d_in[7];
    const float* b2 = (const float*)d_in[8];
    float* out = (float*)d_out;

    char* ws = (char*)d_ws;
    unsigned short* xw01 = (unsigned short*)ws;                 // 25.6 MB
    float* aggH = (float*)(ws + 25600000);                      // 25.6 MB
    unsigned* hw01_u = (unsigned*)(ws + 51200000);              // 6.4 MB
    float* agg2 = (float*)(ws + 57600000);                      // 6.4 MB
    unsigned short* Bt = (unsigned short*)(ws + 64000000);      // 0.2 MB
    int* cnt = (int*)(ws + 64300000);                           // 0.4 MB
    int* off = (int*)(ws + 64800000);                           // 0.4 MB
    int* cursor = (int*)(ws + 65300000);                        // 0.4 MB
    int* bsum = (int*)(ws + 65800000);                          // 2 KB
    int* bsumoff = (int*)(ws + 65810000);                       // 2 KB
    uint2* epk = (uint2*)(ws + 65820000);                       // 12.8 MB -> ~78.6 MB

    // CSR build
    csr_zero<<<NB_SCAN, 256, 0, stream>>>(cnt);
    csr_hist<<<2048, 256, 0, stream>>>(ei, cnt);
    csr_scan1<<<NB_SCAN, 256, 0, stream>>>(cnt, off, bsum);
    csr_scan2<<<1, 512, 0, stream>>>(bsum, bsumoff);
    csr_scan3<<<NB_SCAN, 256, 0, stream>>>(off, bsumoff, cursor);
    csr_scatter<<<2048, 256, 0, stream>>>(ei, ea, cursor, epk);

    // layer 1
    k0_bt<<<192, 256, 0, stream>>>(w1, root1, Bt);
    k1_mfma<<<(N_NODES + 127) / 128, 256, 0, stream>>>(x, Bt, xw01, aggH);
    agg1<<<(N_NODES + 3) / 4, 256, 0, stream>>>(off, cnt, epk, (const unsigned*)xw01, aggH);

    // layer 2
    k3_relu_gemm<<<N_NODES / 16, 256, 0, stream>>>(aggH, b1, w2, root2, hw01_u, agg2);
    agg2_sm<<<N_NODES / 16, 256, 0, stream>>>(off, cnt, epk, hw01_u, agg2, b2, out);
}